// Round 6
// baseline (287.941 us; speedup 1.0000x reference)
//
#include <hip/hip_runtime.h>
#include <hip/hip_bf16.h>
#include <cstdint>
#include <cstddef>

#define BATCH 8192
#define IDIM  768
#define JDIM  768
#define GRID  5
#define KDIM  (IDIM * GRID)   // 3840
#define KC    (KDIM / 32)     // 120 k32-chunks
#define KSPLIT 4
#define KCB   (KC / KSPLIT)   // 30 chunks per gemm block

// ---------------- helpers ----------------

__device__ __forceinline__ unsigned short f2bf(float f) {
    unsigned int u = __float_as_uint(f);
    u += 0x7fffu + ((u >> 16) & 1u);
    return (unsigned short)(u >> 16);
}

typedef __bf16 bf16x8 __attribute__((ext_vector_type(8)));
typedef float  f32x4  __attribute__((ext_vector_type(4)));
typedef unsigned short ushortx8 __attribute__((ext_vector_type(8)));

__device__ __forceinline__ void async_copy16(const void* gsrc, void* ldsdst) {
    __builtin_amdgcn_global_load_lds(
        (const __attribute__((address_space(1))) unsigned int*)gsrc,
        (__attribute__((address_space(3))) unsigned int*)ldsdst,
        16, 0, 0);
}

// Fragment-shuffled layout (16x16x32 MFMA operand order):
//   V[row][k] -> shuf[tile=row>>4][kc=k>>5][lane=(row&15)|(((k>>3)&3)<<4)][e=k&7]
// flat: ((tile*KC + kc)*64 + lane)*8 + e.  One fragment-block = 1KB, wave-contiguous.

// ---------------- basis: A_shuf producer ----------------
// One wave = (bt, kcI), produces ALL 5 g's -> x read exactly once (full 64B lines).
// 3 exps/elem via factorization exp(-5(t-g)^2) = u * C_g * E^{2g}.

__global__ __launch_bounds__(256)
void basis_kernel(const float* __restrict__ x, unsigned short* __restrict__ Ashuf) {
    const int w    = blockIdx.x * 4 + (threadIdx.x >> 6);   // 0..12287
    const int lane = threadIdx.x & 63;
    const int bt   = w / 24;
    const int kcI  = w - bt * 24;
    const int b    = bt * 16 + (lane & 15);
    const int i    = kcI * 32 + (lane >> 4) * 8;

    const float4 x0 = *(const float4*)&x[(size_t)b * IDIM + i];
    const float4 x1 = *(const float4*)&x[(size_t)b * IDIM + i + 4];
    const float xs[8] = {x0.x, x0.y, x0.z, x0.w, x1.x, x1.y, x1.z, x1.w};

    const float C1 = 6.7379469990854670966e-3f;   // e^-5
    const float C2 = 0.28650479686019010032f;     // e^-1.25

    ushortx8 o[GRID];
#pragma unroll
    for (int e = 0; e < 8; ++e) {
        const float e2 = __expf(2.f * xs[e]);                  // tanh, saturates ok
        const float t  = 1.f - 2.f * __builtin_amdgcn_rcpf(e2 + 1.f);
        const float u  = __expf(-5.f * t * t);
        const float E  = __expf(5.f * t);
        const float Ei = __builtin_amdgcn_rcpf(E);
        const float m1 = u * C1, m2 = u * C2;
        o[0][e] = f2bf(m1 * Ei * Ei);
        o[1][e] = f2bf(m2 * Ei);
        o[2][e] = f2bf(u);
        o[3][e] = f2bf(m2 * E);
        o[4][e] = f2bf(m1 * E * E);
    }
#pragma unroll
    for (int g = 0; g < GRID; ++g)
        *(ushortx8*)&Ashuf[((size_t)(bt * KC + g * 24 + kcI) * 64 + lane) * 8] = o[g];
}

// ---------------- Wt + bias: B_shuf producer ----------------
// One wave = (nt, kcI), all 5 g's. blocks [288, 300): bias[j]=sum_i shift[i,j].

__global__ __launch_bounds__(256)
void wtbias_kernel(const float* __restrict__ coeffs,
                   const float* __restrict__ scale,
                   const float* __restrict__ shift,
                   unsigned short* __restrict__ Bshuf,
                   float* __restrict__ bias) {
    const int blk = blockIdx.x;
    const int t   = threadIdx.x;

    if (blk < 288) {
        const int w    = blk * 4 + (t >> 6);                   // 0..1151
        const int lane = t & 63;
        const int nt   = w / 24;
        const int kcI  = w - nt * 24;
        const int j    = nt * 16 + (lane & 15);
        const int i0   = kcI * 32 + (lane >> 4) * 8;

        ushortx8 o[GRID];
#pragma unroll
        for (int e = 0; e < 8; ++e) {
            const int i = i0 + e;
            const float  s  = scale[(size_t)i * JDIM + j];
            const float* cp = &coeffs[((size_t)i * JDIM + j) * GRID];
#pragma unroll
            for (int g = 0; g < GRID; ++g)
                o[g][e] = f2bf(cp[g] * s);
        }
#pragma unroll
        for (int g = 0; g < GRID; ++g)
            *(ushortx8*)&Bshuf[((size_t)(nt * KC + g * 24 + kcI) * 64 + lane) * 8] = o[g];
    } else {
        __shared__ float red[4][64];
        const int j0 = (blk - 288) * 64;
        const int jj = t & 63;
        const int ip = t >> 6;
        float s = 0.f;
        for (int i = ip; i < IDIM; i += 4)
            s += shift[(size_t)i * JDIM + j0 + jj];
        red[ip][jj] = s;
        __syncthreads();
        if (t < 64)
            bias[j0 + t] = red[0][t] + red[1][t] + red[2][t] + red[3][t];
    }
}

// ---------------- MFMA GEMM v6: shuffled operands, LDS-staged, K-split ----------
// Block tile 256(m) x 128(n), 4 waves 2x2, wave tile 128x64 (fm=8, fn=4).
// bytes/MFMA = 375 (vs r2's 583). Grid (6, 32, KSPLIT) = 768 blocks, 2/CU,
// LDS dbuf 48KB. All LDS traffic = contiguous 1KB wave bursts -> 0 conflicts.

__global__ __launch_bounds__(256, 2)
void kan_gemm(const unsigned short* __restrict__ Ashuf,
              const unsigned short* __restrict__ Bshuf,
              const float* __restrict__ bias,
              float* __restrict__ partial,       // [KSPLIT][BATCH][JDIM]
              float* __restrict__ out) {
    __shared__ unsigned short As[2][16 * 512];   // 16 chunks x 1KB per buf
    __shared__ unsigned short Bs[2][8 * 512];    // 8 chunks x 1KB per buf

    const int t    = threadIdx.x;
    const int lane = t & 63;
    const int wave = t >> 6;
    const int mt0  = blockIdx.y * 16;            // 16 m-tiles per block
    const int nt0  = blockIdx.x * 8;             // 8 n-tiles per block
    const int kc0  = blockIdx.z * KCB;
    const int wm   = (wave >> 1) * 8;            // local mt base (0/8)
    const int wn   = (wave & 1) * 4;             // local nt base (0/4)

    f32x4 acc[8][4] = {};

#define STAGE(kc, buf)                                                          \
    {                                                                           \
        _Pragma("unroll")                                                       \
        for (int r = 0; r < 4; ++r) {                                           \
            const int c = r * 4 + wave;                                         \
            async_copy16(Ashuf + ((size_t)(mt0 + c) * KC + (kc)) * 512 + lane * 8, \
                         &As[buf][c * 512 + lane * 8]);                         \
        }                                                                       \
        _Pragma("unroll")                                                       \
        for (int r = 0; r < 2; ++r) {                                           \
            const int c = r * 4 + wave;                                         \
            async_copy16(Bshuf + ((size_t)(nt0 + c) * KC + (kc)) * 512 + lane * 8, \
                         &Bs[buf][c * 512 + lane * 8]);                         \
        }                                                                       \
    }

    STAGE(kc0, 0);
    asm volatile("s_waitcnt vmcnt(0)" ::: "memory");
    __syncthreads();

    for (int it = 0; it < KCB; ++it) {
        const int buf = it & 1;
        if (it + 1 < KCB)
            STAGE(kc0 + it + 1, buf ^ 1);

        bf16x8 a[8], b[4];
#pragma unroll
        for (int f = 0; f < 8; ++f)
            a[f] = *(const bf16x8*)&As[buf][(wm + f) * 512 + lane * 8];
#pragma unroll
        for (int f = 0; f < 4; ++f)
            b[f] = *(const bf16x8*)&Bs[buf][(wn + f) * 512 + lane * 8];
#pragma unroll
        for (int fm = 0; fm < 8; ++fm)
#pragma unroll
            for (int fn = 0; fn < 4; ++fn)
                acc[fm][fn] = __builtin_amdgcn_mfma_f32_16x16x32_bf16(
                    a[fm], b[fn], acc[fm][fn], 0, 0, 0);

        asm volatile("s_waitcnt vmcnt(0)" ::: "memory");
        __syncthreads();
    }
#undef STAGE

    // epilogue: D mapping col=lane&15, row=(lane>>4)*4+reg  [measured m89/m91]
    const bool split = (gridDim.z > 1);
    float* dst = split ? (partial + (size_t)blockIdx.z * BATCH * JDIM) : out;
    const int col   = lane & 15;
    const int rbase = (lane >> 4) * 4;
#pragma unroll
    for (int fm = 0; fm < 8; ++fm) {
        const int rowb = (mt0 + wm + fm) * 16 + rbase;
#pragma unroll
        for (int fn = 0; fn < 4; ++fn) {
            const int j  = (nt0 + wn + fn) * 16 + col;
            const float bj = split ? 0.f : bias[j];
#pragma unroll
            for (int r = 0; r < 4; ++r)
                dst[(size_t)(rowb + r) * JDIM + j] = acc[fm][fn][r] + bj;
        }
    }
}

// ---------------- reduce: out = sum_z partial[z] + bias[j] ----------------

__global__ __launch_bounds__(256)
void reduce_kernel(const float* __restrict__ partial,
                   const float* __restrict__ bias,
                   float* __restrict__ out) {
    const size_t idx4 = ((size_t)blockIdx.x * 256 + threadIdx.x) * 4;
    const size_t PB   = (size_t)BATCH * JDIM;
    float4 s = *(const float4*)(partial + idx4);
#pragma unroll
    for (int z = 1; z < KSPLIT; ++z) {
        const float4 p = *(const float4*)(partial + z * PB + idx4);
        s.x += p.x; s.y += p.y; s.z += p.z; s.w += p.w;
    }
    const int j0 = (int)(idx4 % JDIM);
    const float4 bv = *(const float4*)&bias[j0];
    s.x += bv.x; s.y += bv.y; s.z += bv.z; s.w += bv.w;
    *(float4*)(out + idx4) = s;
}

// ---------------- fallback (ws too small): slow but correct ----------------

__global__ __launch_bounds__(256)
void fallback_kernel(const float* __restrict__ x,
                     const float* __restrict__ coeffs,
                     const float* __restrict__ scale,
                     const float* __restrict__ shift,
                     float* __restrict__ out) {
    __shared__ float bas[KDIM];
    const int b = blockIdx.x;
    const int t = threadIdx.x;
    for (int i = t; i < IDIM; i += 256) {
        float tv = tanhf(x[(size_t)b * IDIM + i]);
#pragma unroll
        for (int g = 0; g < GRID; ++g) {
            float d = tv - (-1.0f + 0.5f * (float)g);
            bas[g * IDIM + i] = __expf(-5.0f * d * d);
        }
    }
    __syncthreads();
#pragma unroll
    for (int jj = 0; jj < 3; ++jj) {
        const int j = t + jj * 256;
        float acc = 0.f;
        for (int i = 0; i < IDIM; ++i) {
            const float sc = scale[(size_t)i * JDIM + j];
            const float* cp = &coeffs[((size_t)i * JDIM + j) * GRID];
            float s5 = 0.f;
#pragma unroll
            for (int g = 0; g < GRID; ++g) s5 += bas[g * IDIM + i] * cp[g];
            acc += s5 * sc + shift[(size_t)i * JDIM + j];
        }
        out[(size_t)b * JDIM + j] = acc;
    }
}

// ---------------- launch ----------------

extern "C" void kernel_launch(void* const* d_in, const int* in_sizes, int n_in,
                              void* d_out, int out_size, void* d_ws, size_t ws_size,
                              hipStream_t stream) {
    const float* x      = (const float*)d_in[0];
    const float* coeffs = (const float*)d_in[1];
    const float* scale  = (const float*)d_in[2];
    const float* shift  = (const float*)d_in[3];
    float* out = (float*)d_out;

    const size_t bshuf_bytes = (size_t)JDIM * KDIM * sizeof(unsigned short);  // 5,898,240
    const size_t bias_off    = bshuf_bytes;
    const size_t bias_bytes  = (size_t)JDIM * sizeof(float);                  // 3,072
    const size_t ashuf_off   = bias_off + bias_bytes;
    const size_t ashuf_bytes = (size_t)BATCH * KDIM * sizeof(unsigned short); // 62,914,560
    const size_t part_off    = ashuf_off + ashuf_bytes;
    const size_t part_bytes  = (size_t)KSPLIT * BATCH * JDIM * sizeof(float); // 100,663,296
    const size_t need_full   = part_off + part_bytes;                         // ~169.5 MB
    const size_t need_mid    = part_off;                                      // ~68.8 MB

    if (ws_size >= need_mid) {
        unsigned short* Bshuf = (unsigned short*)d_ws;
        float*          bias  = (float*)((char*)d_ws + bias_off);
        unsigned short* Ashuf = (unsigned short*)((char*)d_ws + ashuf_off);
        float*          part  = (float*)((char*)d_ws + part_off);

        basis_kernel<<<3072, 256, 0, stream>>>(x, Ashuf);
        wtbias_kernel<<<300, 256, 0, stream>>>(coeffs, scale, shift, Bshuf, bias);
        if (ws_size >= need_full) {
            kan_gemm<<<dim3(JDIM / 128, BATCH / 256, KSPLIT), 256, 0, stream>>>(
                Ashuf, Bshuf, bias, part, out);
            reduce_kernel<<<(BATCH * JDIM) / 1024, 256, 0, stream>>>(part, bias, out);
        } else {
            kan_gemm<<<dim3(JDIM / 128, BATCH / 256, 1), 256, 0, stream>>>(
                Ashuf, Bshuf, bias, (float*)nullptr, out);
        }
    } else {
        fallback_kernel<<<BATCH, 256, 0, stream>>>(x, coeffs, scale, shift, out);
    }
}

// Round 7
// 240.451 us; speedup vs baseline: 1.1975x; 1.1975x over previous
//
#include <hip/hip_runtime.h>
#include <hip/hip_bf16.h>
#include <cstdint>
#include <cstddef>

#define BATCH 8192
#define IDIM  768
#define JDIM  768
#define GRID  5
#define KDIM  (IDIM * GRID)   // 3840

// ---------------- helpers ----------------

__device__ __forceinline__ unsigned short f2bf(float f) {
    unsigned int u = __float_as_uint(f);
    u += 0x7fffu + ((u >> 16) & 1u);
    return (unsigned short)(u >> 16);
}

typedef __bf16 bf16x8 __attribute__((ext_vector_type(8)));
typedef float  f32x4  __attribute__((ext_vector_type(4)));
typedef unsigned short ushortx4 __attribute__((ext_vector_type(4)));
typedef unsigned short ushortx8 __attribute__((ext_vector_type(8)));

__device__ __forceinline__ void async_copy16(const void* gsrc, void* ldsdst) {
    __builtin_amdgcn_global_load_lds(
        (const __attribute__((address_space(1))) unsigned int*)gsrc,
        (__attribute__((address_space(3))) unsigned int*)ldsdst,
        16, 0, 0);
}

// ---------------- fused precompute: basis + Wt + bias, ONE dispatch ----------
// Blocks [0, NBAS): Abas[b][g*768+i] (row-major, GEMM-ready), 8 elems/thread,
//   factorized: exp(-5(t-g)^2) = u * C_g * E^{2g}, u=exp(-5t^2), E=exp(5t).
// Blocks [NBAS, NBAS+NWT): Wt[j][g*768+i] = bf16(coeffs[i,j,g]*scale[i,j])
//   via LDS transpose (r2-proven).
// Blocks [NBAS+NWT, +NBIAS): bias[j] = sum_i shift[i,j].

#define NBAS  ((BATCH * (IDIM / 8)) / 256)          // 3072
#define WT_I 32
#define WT_J 64
#define NWT   ((IDIM / WT_I) * (JDIM / WT_J))       // 288
#define NBIAS (JDIM / 64)                           // 12

__global__ __launch_bounds__(256)
void precompute_kernel(const float* __restrict__ x,
                       const float* __restrict__ coeffs,
                       const float* __restrict__ scale,
                       const float* __restrict__ shift,
                       unsigned short* __restrict__ Wt,
                       float* __restrict__ bias,
                       unsigned short* __restrict__ Abas) {
    __shared__ __align__(16) unsigned short tile[GRID][WT_J][WT_I + 4]; // 23 KB (wt branch)
    __shared__ float red[4][64];
    const int blk = blockIdx.x;
    const int t   = threadIdx.x;

    if (blk < NBAS) {
        // ---- basis: 8 elems/thread, 3 exp + 2 rcp per elem ----
        const int idx = blk * 256 + t;
        const int b  = idx / (IDIM / 8);                    // /96
        const int i0 = (idx - b * (IDIM / 8)) * 8;
        const float4 x0 = *(const float4*)&x[(size_t)b * IDIM + i0];
        const float4 x1 = *(const float4*)&x[(size_t)b * IDIM + i0 + 4];
        const float xs[8] = {x0.x, x0.y, x0.z, x0.w, x1.x, x1.y, x1.z, x1.w};

        const float C1 = 6.7379469990854670966e-3f;   // e^-5
        const float C2 = 0.28650479686019010032f;     // e^-1.25

        ushortx8 o[GRID];
#pragma unroll
        for (int e = 0; e < 8; ++e) {
            const float e2 = __expf(2.f * xs[e]);                  // tanh, saturates ok
            const float tv = 1.f - 2.f * __builtin_amdgcn_rcpf(e2 + 1.f);
            const float u  = __expf(-5.f * tv * tv);
            const float E  = __expf(5.f * tv);
            const float Ei = __builtin_amdgcn_rcpf(E);
            const float m1 = u * C1, m2 = u * C2;
            o[0][e] = f2bf(m1 * Ei * Ei);
            o[1][e] = f2bf(m2 * Ei);
            o[2][e] = f2bf(u);
            o[3][e] = f2bf(m2 * E);
            o[4][e] = f2bf(m1 * E * E);
        }
        unsigned short* p = &Abas[(size_t)b * KDIM + i0];
#pragma unroll
        for (int g = 0; g < GRID; ++g)
            *(ushortx8*)&p[g * IDIM] = o[g];
    } else if (blk < NBAS + NWT) {
        // ---- Wt: LDS transpose (coalesced-per-wave reads, vectorized writes) ----
        const int wblk = blk - NBAS;
        const int i0 = (wblk / (JDIM / WT_J)) * WT_I;
        const int j0 = (wblk % (JDIM / WT_J)) * WT_J;
        const int jj = t & 63;
#pragma unroll
        for (int it = 0; it < (WT_I * WT_J) / 256; ++it) {     // 8 iters
            const int ii = it * 4 + (t >> 6);
            const int i = i0 + ii, j = j0 + jj;
            const float* cp = &coeffs[((size_t)i * JDIM + j) * GRID];
            const float  sc = scale[(size_t)i * JDIM + j];
#pragma unroll
            for (int g = 0; g < GRID; ++g)
                tile[g][jj][ii] = f2bf(cp[g] * sc);
        }
        __syncthreads();
#pragma unroll
        for (int it = 0; it < (WT_J * GRID * (WT_I / 4)) / 256; ++it) { // 10 iters
            const int p  = it * 256 + t;
            const int iq = p & 7;
            const int q  = p >> 3;
            const int g  = q % GRID;
            const int j  = q / GRID;
            ushortx4 v = *(const ushortx4*)&tile[g][j][iq * 4];
            *(ushortx4*)&Wt[(size_t)(j0 + j) * KDIM + g * IDIM + i0 + iq * 4] = v;
        }
    } else {
        // ---- bias ----
        const int j0 = (blk - NBAS - NWT) * 64;
        const int jj = t & 63;
        const int ip = t >> 6;
        float s = 0.f;
        for (int i = ip; i < IDIM; i += 4)
            s += shift[(size_t)i * JDIM + j0 + jj];
        red[ip][jj] = s;
        __syncthreads();
        if (t < 64)
            bias[j0 + t] = red[0][t] + red[1][t] + red[2][t] + red[3][t];
    }
}

// ---------------- MFMA GEMM v7: r2 structure + double-buffer at 512 blocks ----
// BM=128, BN=96, BK=64. Grid 8x64 = 512 = 2/CU balanced. LDS 2x28 KB = 56 KB
// -> still 2 blocks/CU. One barrier per iter; the bottom vmcnt(0) waits on
// loads issued BEFORE the 24 MFMAs -> drain mostly hidden.
// XOR k-chunk swizzle (measured 0 conflicts, r2).

#define BM 128
#define BN 96
#define BK 64

__global__ __launch_bounds__(256, 2)
void kan_gemm(const unsigned short* __restrict__ Abas,  // [BATCH][KDIM]
              const unsigned short* __restrict__ Wt,    // [JDIM][KDIM]
              const float* __restrict__ bias,           // [JDIM]
              float* __restrict__ out) {                // [BATCH][JDIM]
    __shared__ unsigned short As[2][BM * BK];  // 2 x 16 KB
    __shared__ unsigned short Bs[2][BN * BK];  // 2 x 12 KB

    const int t    = threadIdx.x;
    const int lane = t & 63;
    const int wave = t >> 6;
    const int m0 = blockIdx.y * BM;
    const int n0 = blockIdx.x * BN;
    const int wm = (wave >> 1) * 64;   // 0 / 64
    const int wn = (wave & 1) * 48;    // 0 / 48

    f32x4 acc[4][3] = {};

    // staging: thread t -> LDS slot (row=t>>3, chunk lc=t&7); slot holds
    // global chunk cg = lc ^ (row&7).
    const int lrow = t >> 3;
    const int lc   = t & 7;
    const int cg   = lc ^ (lrow & 7);
    const int ldsoff = lrow * BK + lc * 8;
    const size_t abase = (size_t)(m0 + lrow) * KDIM + cg * 8;
    const size_t bbase = (size_t)(n0 + lrow) * KDIM + cg * 8;

#define STAGE(kt, buf)                                                          \
    {                                                                           \
        _Pragma("unroll")                                                       \
        for (int s = 0; s < 4; ++s)                                             \
            async_copy16(&Abas[abase + (size_t)(32 * s) * KDIM + (kt)],         \
                         &As[buf][ldsoff + 32 * s * BK]);                       \
        _Pragma("unroll")                                                       \
        for (int s = 0; s < 3; ++s)                                             \
            async_copy16(&Wt[bbase + (size_t)(32 * s) * KDIM + (kt)],           \
                         &Bs[buf][ldsoff + 32 * s * BK]);                       \
    }

    STAGE(0, 0);
    asm volatile("s_waitcnt vmcnt(0)" ::: "memory");
    __syncthreads();

    for (int it = 0; it < KDIM / BK; ++it) {          // 60 iters
        const int buf = it & 1;
        if (it + 1 < KDIM / BK)
            STAGE((it + 1) * BK, buf ^ 1);            // prefetch into other buf

#pragma unroll
        for (int ks = 0; ks < 2; ++ks) {
            const int pc = ((ks * 4) + (lane >> 4)) ^ (lane & 7);
            bf16x8 af[4], bfr[3];
#pragma unroll
            for (int f = 0; f < 4; ++f)
                af[f]  = *(const bf16x8*)&As[buf][(wm + f * 16 + (lane & 15)) * BK + pc * 8];
#pragma unroll
            for (int f = 0; f < 3; ++f)
                bfr[f] = *(const bf16x8*)&Bs[buf][(wn + f * 16 + (lane & 15)) * BK + pc * 8];
#pragma unroll
            for (int fm = 0; fm < 4; ++fm)
#pragma unroll
                for (int fn = 0; fn < 3; ++fn)
                    acc[fm][fn] = __builtin_amdgcn_mfma_f32_16x16x32_bf16(
                        af[fm], bfr[fn], acc[fm][fn], 0, 0, 0);
        }
        asm volatile("s_waitcnt vmcnt(0)" ::: "memory");  // prefetch landed during MFMAs
        __syncthreads();
    }
#undef STAGE

    // epilogue: D mapping col=lane&15, row=(lane>>4)*4+reg  [measured m89/m91]
    const int col   = lane & 15;
    const int rbase = (lane >> 4) * 4;
#pragma unroll
    for (int fm = 0; fm < 4; ++fm) {
#pragma unroll
        for (int fn = 0; fn < 3; ++fn) {
            const int j  = n0 + wn + fn * 16 + col;
            const float bj = bias[j];
#pragma unroll
            for (int r = 0; r < 4; ++r) {
                const int row = m0 + wm + fm * 16 + rbase + r;
                out[(size_t)row * JDIM + j] = acc[fm][fn][r] + bj;
            }
        }
    }
}

// ---------------- fallback (ws too small): slow but correct ----------------

__global__ __launch_bounds__(256)
void fallback_kernel(const float* __restrict__ x,
                     const float* __restrict__ coeffs,
                     const float* __restrict__ scale,
                     const float* __restrict__ shift,
                     float* __restrict__ out) {
    __shared__ float bas[KDIM];
    const int b = blockIdx.x;
    const int t = threadIdx.x;
    for (int i = t; i < IDIM; i += 256) {
        float tv = tanhf(x[(size_t)b * IDIM + i]);
#pragma unroll
        for (int g = 0; g < GRID; ++g) {
            float d = tv - (-1.0f + 0.5f * (float)g);
            bas[g * IDIM + i] = __expf(-5.0f * d * d);
        }
    }
    __syncthreads();
#pragma unroll
    for (int jj = 0; jj < 3; ++jj) {
        const int j = t + jj * 256;
        float acc = 0.f;
        for (int i = 0; i < IDIM; ++i) {
            const float sc = scale[(size_t)i * JDIM + j];
            const float* cp = &coeffs[((size_t)i * JDIM + j) * GRID];
            float s5 = 0.f;
#pragma unroll
            for (int g = 0; g < GRID; ++g) s5 += bas[g * IDIM + i] * cp[g];
            acc += s5 * sc + shift[(size_t)i * JDIM + j];
        }
        out[(size_t)b * JDIM + j] = acc;
    }
}

// ---------------- launch ----------------

extern "C" void kernel_launch(void* const* d_in, const int* in_sizes, int n_in,
                              void* d_out, int out_size, void* d_ws, size_t ws_size,
                              hipStream_t stream) {
    const float* x      = (const float*)d_in[0];
    const float* coeffs = (const float*)d_in[1];
    const float* scale  = (const float*)d_in[2];
    const float* shift  = (const float*)d_in[3];
    float* out = (float*)d_out;

    const size_t wt_bytes   = (size_t)JDIM * KDIM * sizeof(unsigned short); // 5,898,240
    const size_t bias_off   = wt_bytes;
    const size_t bias_bytes = (size_t)JDIM * sizeof(float);
    const size_t bas_off    = bias_off + bias_bytes;
    const size_t bas_bytes  = (size_t)BATCH * KDIM * sizeof(unsigned short);
    const size_t need       = bas_off + bas_bytes;                          // ~68.8 MB

    if (ws_size >= need) {
        unsigned short* Wt   = (unsigned short*)d_ws;
        float*          bias = (float*)((char*)d_ws + bias_off);
        unsigned short* Abas = (unsigned short*)((char*)d_ws + bas_off);

        precompute_kernel<<<NBAS + NWT + NBIAS, 256, 0, stream>>>(
            x, coeffs, scale, shift, Wt, bias, Abas);
        kan_gemm<<<dim3(JDIM / BN, BATCH / BM), 256, 0, stream>>>(Abas, Wt, bias, out);
    } else {
        fallback_kernel<<<BATCH, 256, 0, stream>>>(x, coeffs, scale, shift, out);
    }
}